// Round 1
// 750.743 us; speedup vs baseline: 1.0242x; 1.0242x over previous
//
#include <hip/hip_runtime.h>
#include <stdint.h>

// Shapes (fixed): V=32000, E=512, H=1024, A=512, L=2, B=64, S=128
#define HD    1024
#define BATCH 64
#define SEQ   128
#define AD    512
#define EMBD  512
#define VOCAB 32000

typedef float f32x4 __attribute__((ext_vector_type(4)));
typedef short bf8   __attribute__((ext_vector_type(8)));

// ---- workspace layout (float offsets; bf16 regions hold 2 shorts per float) ----
#define WS_SCOREP 0          // 4 x (64*128) f32 score partial slabs
#define WS_DECP   32768      // 64*512 f32
#define WS_G0     65536      // 4 x (64*4096) f32 gate partial slabs L0
#define WS_G1     1114112    // 4 x (64*4096) f32 gate partial slabs L1
#define WS_LCTX   2162688    // 64*32000 f32 fc ctx-part partial
#define WS_X0BF   4210688    // bf16 64x2560 [emb | ctx]
#define WS_XFCBF  4292608    // bf16 64x3072 [h1 | ctx]
#define WS_HIDBF  4390912    // bf16 2x64x1024 (hidden both layers)
#define WS_WENCBF 4456448    // bf16 512x2048
#define WS_H0BF   4980736    // bf16 64x1024

// output layout (floats)
#define OUT_LOGITS 0
#define OUT_HID    2048000
#define OUT_CELL   2179072
#define OUT_ALPHA  2310144

__device__ __forceinline__ short f2bf(float f) {
  uint32_t u = __float_as_uint(f);
  u += 0x7FFF + ((u >> 16) & 1);   // RNE
  return (short)(u >> 16);
}

__device__ __forceinline__ void store_bf4(short* p, float4 v) {
  short4 s;
  s.x = f2bf(v.x); s.y = f2bf(v.y); s.z = f2bf(v.z); s.w = f2bf(v.w);
  *(short4*)p = s;
}

// ---------------------------------------------------------------------------
// gemm_f32A: one 64x64 tile at column n0. A f32 (64 x K), B f32 (N x K).
// (only used for dec_proj inside k_prep)
// ---------------------------------------------------------------------------
__device__ __forceinline__ void gemm_f32A(
    short (*As)[72], short (*Bs)[72],
    const float* __restrict__ A, int lda,
    const float* __restrict__ Bm, int ldb, int K_total, int n0,
    float* __restrict__ C, int ldc, const float* __restrict__ bias) {
  const int tid = threadIdx.x;
  const int wave = tid >> 6, lane = tid & 63;
  const int quad = lane >> 4, l16 = lane & 15;
  const int srow = tid >> 4, sc4 = (tid & 15) * 4;

  f32x4 acc[4];
#pragma unroll
  for (int i = 0; i < 4; ++i) acc[i] = (f32x4){0.f, 0.f, 0.f, 0.f};

  float4 pa[4], pb[4];
#pragma unroll
  for (int p = 0; p < 4; ++p) {
    int row = srow + p * 16;
    pa[p] = *(const float4*)&A[(size_t)row * lda + sc4];
    pb[p] = *(const float4*)&Bm[(size_t)(n0 + row) * ldb + sc4];
  }

  for (int kt = 0; kt < K_total; kt += 64) {
#pragma unroll
    for (int p = 0; p < 4; ++p) {
      int row = srow + p * 16;
      store_bf4(&As[row][sc4], pa[p]);
      store_bf4(&Bs[row][sc4], pb[p]);
    }
    __syncthreads();
    if (kt + 64 < K_total) {
      int kn = kt + 64;
#pragma unroll
      for (int p = 0; p < 4; ++p) {
        int row = srow + p * 16;
        pa[p] = *(const float4*)&A[(size_t)row * lda + kn + sc4];
        pb[p] = *(const float4*)&Bm[(size_t)(n0 + row) * ldb + kn + sc4];
      }
    }
#pragma unroll
    for (int kk = 0; kk < 64; kk += 32) {
      bf8 af = *(const bf8*)&As[wave * 16 + l16][kk + quad * 8];
#pragma unroll
      for (int ns = 0; ns < 4; ++ns) {
        bf8 bq = *(const bf8*)&Bs[ns * 16 + l16][kk + quad * 8];
        acc[ns] = __builtin_amdgcn_mfma_f32_16x16x32_bf16(af, bq, acc[ns], 0, 0, 0);
      }
    }
    __syncthreads();
  }

#pragma unroll
  for (int ns = 0; ns < 4; ++ns) {
    int n = n0 + ns * 16 + l16;
    float bv = bias ? bias[n] : 0.f;
#pragma unroll
    for (int r = 0; r < 4; ++r) {
      int m = wave * 16 + quad * 4 + r;
      C[(size_t)m * ldc + n] = acc[ns][r] + bv;
    }
  }
}

// ---------------------------------------------------------------------------
// gemm_bf16A: one 64x64 tile at column n0; A is PRE-CONVERTED bf16 (no VALU
// convert on the A path, 16B direct LDS stores). Virtual K axis from
// (A1,B1) for kv<K1 then (A2,B2). Tiles [t0, t0+ntiles). Optional bias and
// fp32 partial-add (Cadd).
// ---------------------------------------------------------------------------
__device__ __forceinline__ void gemm_bf16A(
    short (*As)[72], short (*Bs)[72],
    const short* __restrict__ A1, int lda1, int K1,
    const float* __restrict__ B1, int ldb1,
    const short* __restrict__ A2, int lda2,
    const float* __restrict__ B2, int ldb2,
    int t0, int ntiles, int n0,
    float* __restrict__ C, int ldc,
    const float* __restrict__ bias,
    const float* __restrict__ Cadd, int ldadd) {
  const int tid = threadIdx.x;
  const int wave = tid >> 6, lane = tid & 63;
  const int quad = lane >> 4, l16 = lane & 15;
  const int arow = tid >> 3, ac8 = (tid & 7) * 8;   // A: 32 rows/pass, 16B lanes
  const int brow = tid >> 4, bc4 = (tid & 15) * 4;  // B: 16 rows/pass, float4

  f32x4 acc[4];
#pragma unroll
  for (int i = 0; i < 4; ++i) acc[i] = (f32x4){0.f, 0.f, 0.f, 0.f};

  bf8 qa[2];
  float4 pb[4];
  auto loadAB = [&](int tile) {
    int kv = tile * 64;
    const short* Ap; const float* Bp; int la, lb, ko;
    if (kv < K1) { Ap = A1; Bp = B1; la = lda1; lb = ldb1; ko = kv; }
    else         { Ap = A2; Bp = B2; la = lda2; lb = ldb2; ko = kv - K1; }
#pragma unroll
    for (int p = 0; p < 2; ++p)
      qa[p] = *(const bf8*)&Ap[(size_t)(arow + p * 32) * la + ko + ac8];
#pragma unroll
    for (int p = 0; p < 4; ++p)
      pb[p] = *(const float4*)&Bp[(size_t)(n0 + brow + p * 16) * lb + ko + bc4];
  };

  loadAB(t0);
  for (int ti = t0; ti < t0 + ntiles; ++ti) {
#pragma unroll
    for (int p = 0; p < 2; ++p) *(bf8*)&As[arow + p * 32][ac8] = qa[p];
#pragma unroll
    for (int p = 0; p < 4; ++p) store_bf4(&Bs[brow + p * 16][bc4], pb[p]);
    __syncthreads();
    if (ti + 1 < t0 + ntiles) loadAB(ti + 1);
#pragma unroll
    for (int kk = 0; kk < 64; kk += 32) {
      bf8 af = *(const bf8*)&As[wave * 16 + l16][kk + quad * 8];
#pragma unroll
      for (int ns = 0; ns < 4; ++ns) {
        bf8 bq = *(const bf8*)&Bs[ns * 16 + l16][kk + quad * 8];
        acc[ns] = __builtin_amdgcn_mfma_f32_16x16x32_bf16(af, bq, acc[ns], 0, 0, 0);
      }
    }
    __syncthreads();
  }

#pragma unroll
  for (int ns = 0; ns < 4; ++ns) {
    int n = n0 + ns * 16 + l16;
    float bv = bias ? bias[n] : 0.f;
#pragma unroll
    for (int r = 0; r < 4; ++r) {
      int m = wave * 16 + quad * 4 + r;
      float v = acc[ns][r] + bv;
      if (Cadd) v += Cadd[(size_t)m * ldadd + n];
      C[(size_t)m * ldc + n] = v;
    }
  }
}

// ---------------------------------------------------------------------------
// k_prep: block-partitioned independent prologue work in ONE launch:
//   [0,8)    dec_proj = hidden[1] @ W_dec^T (f32-A gemm, longest -> first)
//   [8,40)   emb gather -> x0bf[:, :512] (bf16)
//   [40,168) hidden (2,64,1024) f32 -> hidbf
//   [168,680) W_enc (512x2048) f32 -> wencbf
// ---------------------------------------------------------------------------
__global__ __launch_bounds__(256) void k_prep(
    float* __restrict__ ws, const int* __restrict__ token,
    const float* __restrict__ emb, const float* __restrict__ hidden,
    const float* __restrict__ Wenc, const float* __restrict__ Wdec) {
  __shared__ __align__(16) short As[64][72];
  __shared__ __align__(16) short Bs[64][72];
  const int bx = blockIdx.x, t = threadIdx.x;
  if (bx < 8) {
    gemm_f32A(As, Bs, hidden + BATCH * HD, HD, Wdec, HD, 1024, bx * 64,
              ws + WS_DECP, AD, nullptr);
    return;
  }
  if (bx < 40) {                       // emb gather
    int idx = (bx - 8) * 256 + t;      // 0..8191
    int b = idx >> 7, e4 = (idx & 127) * 4;
    int tok = token[b];
    float4 v = *(const float4*)&emb[(size_t)tok * EMBD + e4];
    store_bf4((short*)(ws + WS_X0BF) + (size_t)b * 2560 + e4, v);
    return;
  }
  if (bx < 168) {                      // hidden -> bf16
    int idx = (bx - 40) * 256 + t;     // 0..32767
    float4 v = *(const float4*)&hidden[(size_t)idx * 4];
    store_bf4((short*)(ws + WS_HIDBF) + (size_t)idx * 4, v);
    return;
  }
  // W_enc -> bf16 (8 elements / thread)
  int idx = (bx - 168) * 256 + t;      // 0..131071
  size_t base = (size_t)idx * 8;
  float4 v0 = *(const float4*)&Wenc[base];
  float4 v1 = *(const float4*)&Wenc[base + 4];
  short* dst = (short*)(ws + WS_WENCBF) + base;
  store_bf4(dst, v0);
  store_bf4(dst + 4, v1);
}

// ---------------------------------------------------------------------------
// k_attn: fused enc_proj GEMM + tanh + v-dot -> score partial slabs.
// B-operand (W_enc) now pre-converted bf16: direct 16B LDS stores, no VALU.
// grid (128 mblk, 4 nblk), 256 thr. Tile M=64 x N=128, reg-prefetch.
// ---------------------------------------------------------------------------
__global__ __launch_bounds__(256) void k_attn(
    const float* __restrict__ enc, const short* __restrict__ wencbf,
    const float* __restrict__ dec_proj, const float* __restrict__ vw,
    float* __restrict__ scorep) {
  __shared__ __align__(16) short As[64][72];
  __shared__ __align__(16) short Bs[128][72];
  const int tid = threadIdx.x;
  const int wave = tid >> 6, lane = tid & 63;
  const int quad = lane >> 4, l16 = lane & 15;
  const int mblk = blockIdx.x, nblk = blockIdx.y;
  const int b = mblk >> 1, s0 = (mblk & 1) * 64;
  const int n0 = nblk * 128;
  const size_t abase = ((size_t)s0 * BATCH + b) * 2048;
  const int srow = tid >> 4, sc4 = (tid & 15) * 4;
  const int brow = tid >> 3, bc8 = (tid & 7) * 8;

  f32x4 acc[8];
#pragma unroll
  for (int i = 0; i < 8; ++i) acc[i] = (f32x4){0.f, 0.f, 0.f, 0.f};

  float4 pa[4];
  bf8 qb[4];
  auto loadAB = [&](int kt) {
#pragma unroll
    for (int p = 0; p < 4; ++p) {
      int row = srow + p * 16;
      pa[p] = *(const float4*)&enc[abase + (size_t)row * (BATCH * 2048) + kt + sc4];
    }
#pragma unroll
    for (int p = 0; p < 4; ++p)
      qb[p] = *(const bf8*)&wencbf[(size_t)(n0 + brow + p * 32) * 2048 + kt + bc8];
  };

  loadAB(0);
  for (int kt = 0; kt < 2048; kt += 64) {
#pragma unroll
    for (int p = 0; p < 4; ++p) store_bf4(&As[srow + p * 16][sc4], pa[p]);
#pragma unroll
    for (int p = 0; p < 4; ++p) *(bf8*)&Bs[brow + p * 32][bc8] = qb[p];
    __syncthreads();
    if (kt + 64 < 2048) loadAB(kt + 64);
#pragma unroll
    for (int kk = 0; kk < 64; kk += 32) {
      bf8 af = *(const bf8*)&As[wave * 16 + l16][kk + quad * 8];
#pragma unroll
      for (int ns = 0; ns < 8; ++ns) {
        bf8 bq = *(const bf8*)&Bs[ns * 16 + l16][kk + quad * 8];
        acc[ns] = __builtin_amdgcn_mfma_f32_16x16x32_bf16(af, bq, acc[ns], 0, 0, 0);
      }
    }
    __syncthreads();
  }

  float part[4] = {0.f, 0.f, 0.f, 0.f};
#pragma unroll
  for (int ns = 0; ns < 8; ++ns) {
    int n = n0 + ns * 16 + l16;
    float dp = dec_proj[b * AD + n];
    float vv = vw[n];
#pragma unroll
    for (int r = 0; r < 4; ++r) part[r] += tanhf(acc[ns][r] + dp) * vv;
  }
#pragma unroll
  for (int r = 0; r < 4; ++r) {
    float v = part[r];
    v += __shfl_xor(v, 1);
    v += __shfl_xor(v, 2);
    v += __shfl_xor(v, 4);
    v += __shfl_xor(v, 8);
    if (l16 == 0)
      scorep[nblk * (BATCH * SEQ) + mblk * 64 + wave * 16 + quad * 4 + r] = v;
  }
}

// ---------------------------------------------------------------------------
// k_softmax_ctx: sum 4 score slabs, softmax over S=128, write alpha (f32);
// context -> bf16 into x0bf[b,512+d] and xfcbf[b,1024+d]. grid (64,2).
// ---------------------------------------------------------------------------
__global__ __launch_bounds__(256) void k_softmax_ctx(
    const float* __restrict__ scorep, const float* __restrict__ enc,
    float* __restrict__ alpha_out, short* __restrict__ x0bf,
    short* __restrict__ xfcbf) {
  const int b = blockIdx.x, dchunk = blockIdx.y, t = threadIdx.x;
  __shared__ float al[128];
  __shared__ float buf[128];
  float sv = 0.f;
  if (t < 128) {
    sv = scorep[b * SEQ + t] + scorep[8192 + b * SEQ + t]
       + scorep[16384 + b * SEQ + t] + scorep[24576 + b * SEQ + t];
    buf[t] = sv;
  }
  __syncthreads();
  for (int off = 64; off > 0; off >>= 1) {
    if (t < off) buf[t] = fmaxf(buf[t], buf[t + off]);
    __syncthreads();
  }
  float mx = buf[0];
  __syncthreads();
  float e = 0.f;
  if (t < 128) { e = __expf(sv - mx); buf[t] = e; }
  __syncthreads();
  for (int off = 64; off > 0; off >>= 1) {
    if (t < off) buf[t] += buf[t + off];
    __syncthreads();
  }
  float inv = 1.f / buf[0];
  if (t < 128) {
    float a = e * inv;
    al[t] = a;
    if (dchunk == 0) alpha_out[b * SEQ + t] = a;
  }
  __syncthreads();

  const int d = dchunk * 1024 + t * 4;
  float4 acc = make_float4(0.f, 0.f, 0.f, 0.f);
#pragma unroll 4
  for (int s = 0; s < SEQ; ++s) {
    float4 ev = *(const float4*)&enc[((size_t)s * BATCH + b) * 2048 + d];
    float w = al[s];
    acc.x += w * ev.x; acc.y += w * ev.y;
    acc.z += w * ev.z; acc.w += w * ev.w;
  }
  store_bf4(&x0bf[(size_t)b * 2560 + 512 + d], acc);
  store_bf4(&xfcbf[(size_t)b * 3072 + 1024 + d], acc);
}

// ---------------------------------------------------------------------------
// k_big0: ONE launch streaming fc_W ctx-half CONCURRENTLY with gates0.
//   blocks [0,500):  logits_ctx = ctx @ fc_W[:,1024:3072]^T   (K=2048)
//   blocks [500,756): gates0 slabs = x0 @ W_ih0^T + hid0 @ W_hh0^T (vK=3584)
// fc blocks first: longest-running work dispatched earliest.
// ---------------------------------------------------------------------------
__global__ __launch_bounds__(256) void k_big0(
    float* __restrict__ ws, const float* __restrict__ W_ih0,
    const float* __restrict__ W_hh0, const float* __restrict__ fc_W) {
  __shared__ __align__(16) short As[64][72];
  __shared__ __align__(16) short Bs[64][72];
  const short* x0bf   = (const short*)(ws + WS_X0BF);
  const short* hid0bf = (const short*)(ws + WS_HIDBF);
  const short* xfcbf  = (const short*)(ws + WS_XFCBF);
  int bx = blockIdx.x;
  if (bx < 500) {
    gemm_bf16A(As, Bs,
               xfcbf + 1024, 3072, 2048, fc_W + 1024, 3072,
               xfcbf + 1024, 3072, fc_W + 1024, 3072,   // unused second source
               0, 32, bx * 64,
               ws + WS_LCTX, VOCAB, nullptr, nullptr, 0);
  } else {
    int g = bx - 500;
    int nblk = g & 63, z = g >> 6;
    gemm_bf16A(As, Bs,
               x0bf, 2560, 2560, W_ih0, 2560,
               hid0bf, 1024, W_hh0, 1024,
               z * 14, 14, nblk * 64,
               ws + WS_G0 + (size_t)z * (64 * 4096), 4096, nullptr, nullptr, 0);
  }
}

// ---------------------------------------------------------------------------
// k_gates1: gates1 slabs = h0 @ W_ih1^T + hidden[1] @ W_hh1^T (vK=2048).
// grid 256 (64 nblk x 4 z).
// ---------------------------------------------------------------------------
__global__ __launch_bounds__(256) void k_gates1(
    float* __restrict__ ws, const float* __restrict__ W_ih1,
    const float* __restrict__ W_hh1) {
  __shared__ __align__(16) short As[64][72];
  __shared__ __align__(16) short Bs[64][72];
  const short* h0bf   = (const short*)(ws + WS_H0BF);
  const short* hid1bf = (const short*)(ws + WS_HIDBF) + BATCH * HD;
  int nblk = blockIdx.x & 63, z = blockIdx.x >> 6;
  gemm_bf16A(As, Bs,
             h0bf, 1024, 1024, W_ih1, 1024,
             hid1bf, 1024, W_hh1, 1024,
             z * 8, 8, nblk * 64,
             ws + WS_G1 + (size_t)z * (64 * 4096), 4096, nullptr, nullptr, 0);
}

// ---------------------------------------------------------------------------
// k_fc_h1: logits = h1 @ fc_W[:,0:1024]^T + logits_ctx + fc_b  (K=1024 tail).
// grid 500.
// ---------------------------------------------------------------------------
__global__ __launch_bounds__(256) void k_fc_h1(
    float* __restrict__ ws, const float* __restrict__ fc_W,
    const float* __restrict__ fc_b, float* __restrict__ out_logits) {
  __shared__ __align__(16) short As[64][72];
  __shared__ __align__(16) short Bs[64][72];
  const short* xfcbf = (const short*)(ws + WS_XFCBF);
  gemm_bf16A(As, Bs,
             xfcbf, 3072, 1024, fc_W, 3072,
             xfcbf, 3072, fc_W, 3072,                   // unused second source
             0, 16, blockIdx.x * 64,
             out_logits, VOCAB, fc_b, ws + WS_LCTX, VOCAB);
}

// ---------------------------------------------------------------------------
// k_act: LSTM cell elementwise over 4 gate partial slabs + biases.
// Writes f32 h/c to out and bf16 h to the next GEMM's A buffer.
// ---------------------------------------------------------------------------
__global__ __launch_bounds__(256) void k_act(
    const float* __restrict__ gslab,
    const float* __restrict__ b_ih, const float* __restrict__ b_hh,
    const float* __restrict__ cell_in,
    float* __restrict__ hid_out, float* __restrict__ cell_out,
    short* __restrict__ hbf, int hstride) {
  int idx = blockIdx.x * 256 + threadIdx.x;   // < 65536
  int b = idx >> 10, n = idx & 1023;
  float gi = b_ih[n]        + b_hh[n];
  float gf = b_ih[1024 + n] + b_hh[1024 + n];
  float gg = b_ih[2048 + n] + b_hh[2048 + n];
  float go = b_ih[3072 + n] + b_hh[3072 + n];
#pragma unroll
  for (int sl = 0; sl < 4; ++sl) {
    const float* g = gslab + (size_t)sl * (64 * 4096) + (size_t)b * 4096;
    gi += g[n];
    gf += g[1024 + n];
    gg += g[2048 + n];
    go += g[3072 + n];
  }
  float i = 1.f / (1.f + __expf(-gi));
  float f = 1.f / (1.f + __expf(-gf));
  float o = 1.f / (1.f + __expf(-go));
  float c = f * cell_in[idx] + i * tanhf(gg);
  float h = o * tanhf(c);
  cell_out[idx] = c;
  hid_out[idx] = h;
  hbf[(size_t)b * hstride + n] = f2bf(h);
}

// ---------------------------------------------------------------------------
extern "C" void kernel_launch(void* const* d_in, const int* in_sizes, int n_in,
                              void* d_out, int out_size, void* d_ws, size_t ws_size,
                              hipStream_t stream) {
  const int*   token  = (const int*)d_in[0];
  const float* hidden = (const float*)d_in[1];   // (2,64,1024)
  const float* cell   = (const float*)d_in[2];   // (2,64,1024)
  const float* enc    = (const float*)d_in[3];   // (128,64,2048)
  const float* emb    = (const float*)d_in[4];   // (32000,512)
  const float* W_enc  = (const float*)d_in[5];   // (512,2048)
  const float* W_dec  = (const float*)d_in[6];   // (512,1024)
  const float* v_w    = (const float*)d_in[7];   // (512,)
  const float* W_ih0  = (const float*)d_in[8];   // (4096,2560)
  const float* W_hh0  = (const float*)d_in[9];   // (4096,1024)
  const float* b_ih0  = (const float*)d_in[10];
  const float* b_hh0  = (const float*)d_in[11];
  const float* W_ih1  = (const float*)d_in[12];  // (4096,1024)
  const float* W_hh1  = (const float*)d_in[13];  // (4096,1024)
  const float* b_ih1  = (const float*)d_in[14];
  const float* b_hh1  = (const float*)d_in[15];
  const float* fc_W   = (const float*)d_in[16];  // (32000,3072)
  const float* fc_b   = (const float*)d_in[17];

  float* out = (float*)d_out;
  float* ws  = (float*)d_ws;

  // 1. prologue: dec_proj GEMM || emb gather->bf16 || hidden->bf16 || W_enc->bf16
  k_prep<<<680, 256, 0, stream>>>(ws, token, emb, hidden, W_enc, W_dec);

  // 2. fused enc_proj + tanh + v-dot -> score partial slabs
  k_attn<<<dim3(128, 4), 256, 0, stream>>>(
      enc, (const short*)(ws + WS_WENCBF), ws + WS_DECP, v_w, ws + WS_SCOREP);

  // 3. softmax + context (alpha f32 out; ctx bf16 into x0bf / xfcbf)
  k_softmax_ctx<<<dim3(64, 2), 256, 0, stream>>>(
      ws + WS_SCOREP, enc, out + OUT_ALPHA,
      (short*)(ws + WS_X0BF), (short*)(ws + WS_XFCBF));

  // 4. fc ctx-half (262 MB) streamed concurrently with gates0 (59 MB)
  k_big0<<<756, 256, 0, stream>>>(ws, W_ih0, W_hh0, fc_W);

  // 5. LSTM cell 0 -> out hidden[0]/cell[0], h0 bf16 scratch
  k_act<<<256, 256, 0, stream>>>(ws + WS_G0, b_ih0, b_hh0, cell,
                                 out + OUT_HID, out + OUT_CELL,
                                 (short*)(ws + WS_H0BF), HD);

  // 6. gates1 slabs
  k_gates1<<<256, 256, 0, stream>>>(ws, W_ih1, W_hh1);

  // 7. LSTM cell 1 -> out hidden[1]/cell[1], h1 bf16 into xfcbf[:, :1024]
  k_act<<<256, 256, 0, stream>>>(ws + WS_G1, b_ih1, b_hh1, cell + BATCH * HD,
                                 out + OUT_HID + BATCH * HD,
                                 out + OUT_CELL + BATCH * HD,
                                 (short*)(ws + WS_XFCBF), 3072);

  // 8. fc h1-half tail (131 MB) + ctx partial + bias -> logits
  k_fc_h1<<<500, 256, 0, stream>>>(ws, fc_W, fc_b, out + OUT_LOGITS);
}